// Round 10
// baseline (343.295 us; speedup 1.0000x reference)
//
#include <hip/hip_runtime.h>

// SelfAttn (SAGAN block): B=4, C=512, N=4096, C8=64
// out = gamma * (V @ softmax(Q K^T)^T) + x ; also outputs attention [B,N,N].
// All GEMMs via v_mfma_f32_16x16x32_bf16; fp32 accumulate.
// R10: fused kernel, barrier amortized 4x (4 chunks per sync period,
// double-buffered 32KB P tiles, lgkm-only barriers: 17 instead of 64).

#define BB 4
#define CC 512
#define NN 4096
#define C8V 64

typedef __bf16 bf16x8 __attribute__((ext_vector_type(8)));
typedef float f32x4 __attribute__((ext_vector_type(4)));
typedef float f32x4v __attribute__((ext_vector_type(4)));   // for nontemporal builtins
typedef unsigned short u16x8 __attribute__((ext_vector_type(8)));

#if __has_builtin(__builtin_amdgcn_exp2f)
#define EXP2(x) __builtin_amdgcn_exp2f(x)
#else
#define EXP2(x) exp2f(x)
#endif

#define MFMA16(a, b, c) __builtin_amdgcn_mfma_f32_16x16x32_bf16((a), (b), (c), 0, 0, 0)

__device__ __forceinline__ unsigned short f2b(float f) {
  union { float f; unsigned u; } x; x.f = f;
  unsigned u = x.u;
  u += 0x7fffu + ((u >> 16) & 1u);   // RNE round to bf16
  return (unsigned short)(u >> 16);
}

__device__ __forceinline__ bf16x8 ldb8(const unsigned short* p) {
  return *reinterpret_cast<const bf16x8*>(p);
}

// ---------------- weights fp32 -> bf16 ----------------
__global__ __launch_bounds__(256) void k_cvt_w(
    const float* __restrict__ wq, const float* __restrict__ wk, const float* __restrict__ wv,
    unsigned short* __restrict__ wqb, unsigned short* __restrict__ wkb, unsigned short* __restrict__ wvb) {
  int i = blockIdx.x * 256 + threadIdx.x;
  if (i < 32768)        wqb[i] = f2b(wq[i]);
  else if (i < 65536)   wkb[i - 32768] = f2b(wk[i - 32768]);
  else if (i < 327680)  wvb[i - 65536] = f2b(wv[i - 65536]);
}

// ---------------- transpose [C][N] f32 -> [N][C] bf16 (per batch) ----------------
__global__ __launch_bounds__(256) void k_transpose(const float* __restrict__ src,
                                                   unsigned short* __restrict__ dst) {
  __shared__ float tile[64][65];
  int b = blockIdx.z, c0 = blockIdx.y * 64, n0 = blockIdx.x * 64;
  const float* s = src + (size_t)b * CC * NN;
  unsigned short* d = dst + (size_t)b * NN * CC;
  int t = threadIdx.x;
#pragma unroll
  for (int j = 0; j < 4; j++) {
    int idx = t + j * 256, row = idx >> 4, col4 = (idx & 15) * 4;
    f32x4v v4 = *reinterpret_cast<const f32x4v*>(&s[(size_t)(c0 + row) * NN + n0 + col4]);
    tile[row][col4 + 0] = v4.x; tile[row][col4 + 1] = v4.y;
    tile[row][col4 + 2] = v4.z; tile[row][col4 + 3] = v4.w;
  }
  __syncthreads();
#pragma unroll
  for (int j = 0; j < 4; j++) {
    int idx = t + j * 256, nrow = idx >> 4, c4 = (idx & 15) * 4;
    ushort4 o;
    o.x = f2b(tile[c4 + 0][nrow]); o.y = f2b(tile[c4 + 1][nrow]);
    o.z = f2b(tile[c4 + 2][nrow]); o.w = f2b(tile[c4 + 3][nrow]);
    *reinterpret_cast<ushort4*>(&d[(size_t)(n0 + nrow) * CC + c0 + c4]) = o;
  }
}

// ---------------- Q/K projection: [M=16384][512] x [64][512]^T -> [M][64] bf16 ----------------
__global__ __launch_bounds__(256) void k_proj64(const unsigned short* __restrict__ aT,
                                                const unsigned short* __restrict__ wb,
                                                const float* __restrict__ bias,
                                                unsigned short* __restrict__ out, float scale) {
  int wave = threadIdx.x >> 6, l = threadIdx.x & 63;
  int r0 = blockIdx.x * 64 + wave * 16;
  int lr = l & 15, lk = l >> 4;
  const unsigned short* arow = aT + (size_t)(r0 + lr) * CC + lk * 8;
  f32x4 acc[4] = {};
  for (int ks = 0; ks < 16; ks++) {
    bf16x8 a = ldb8(arow + ks * 32);
#pragma unroll
    for (int cg = 0; cg < 4; cg++) {
      bf16x8 bfr = ldb8(wb + (size_t)(cg * 16 + lr) * CC + ks * 32 + lk * 8);
      acc[cg] = MFMA16(a, bfr, acc[cg]);
    }
  }
#pragma unroll
  for (int cg = 0; cg < 4; cg++) {
    int o = cg * 16 + lr;
    float bv = bias[o];
#pragma unroll
    for (int i = 0; i < 4; i++) {
      int row = r0 + lk * 4 + i;
      out[(size_t)row * C8V + o] = f2b((acc[cg][i] + bv) * scale);
    }
  }
}

// ---------------- V projection: wv[512][512] x xT[b][N][512] -> v[b][512][N] bf16 ----------------
__global__ __launch_bounds__(256) void k_projv(const unsigned short* __restrict__ wvb,
                                               const unsigned short* __restrict__ xT,
                                               const float* __restrict__ bv,
                                               unsigned short* __restrict__ v) {
  int b = blockIdx.z, c0 = blockIdx.y * 64;
  int wave = threadIdx.x >> 6, l = threadIdx.x & 63;
  int n0 = blockIdx.x * 256 + wave * 64;
  int lr = l & 15, lk = l >> 4;
  const unsigned short* xb = xT + (size_t)b * NN * CC;
  f32x4 acc[4][4] = {};
  for (int ks = 0; ks < 16; ks++) {
    bf16x8 a[4], bfr[4];
#pragma unroll
    for (int rg = 0; rg < 4; rg++)
      a[rg] = ldb8(wvb + (size_t)(c0 + rg * 16 + lr) * CC + ks * 32 + lk * 8);
#pragma unroll
    for (int cg = 0; cg < 4; cg++)
      bfr[cg] = ldb8(xb + (size_t)(n0 + cg * 16 + lr) * CC + ks * 32 + lk * 8);
#pragma unroll
    for (int rg = 0; rg < 4; rg++)
#pragma unroll
      for (int cg = 0; cg < 4; cg++)
        acc[rg][cg] = MFMA16(a[rg], bfr[cg], acc[rg][cg]);
  }
  unsigned short* vb = v + (size_t)b * CC * NN;
#pragma unroll
  for (int rg = 0; rg < 4; rg++)
#pragma unroll
    for (int i = 0; i < 4; i++) {
      int row = c0 + rg * 16 + lk * 4 + i;
      float bias = bv[row];
#pragma unroll
      for (int cg = 0; cg < 4; cg++) {
        int col = n0 + cg * 16 + lr;
        vb[(size_t)row * NN + col] = f2b(acc[rg][cg][i] + bias);
      }
    }
}

// ---------------- fused: energy + softmax + att write + PV + epilogue ----------------
// Grid 256 (1 block/CU), XCD-pinned. Pass 2 processes FOUR 64-col chunks per
// sync period: {QK^T + softmax + att-store + P->LDS} x4 into one 32KB buffer,
// ONE lgkm-only barrier, then {v-load + PV} x4. Double-buffered (2x32KB LDS).
// Barriers: 17 total instead of 64 -> per-barrier cost amortized 4x; within
// each region the compiler has 4 chunks of independent loads/MFMAs for ILP.
__global__ __launch_bounds__(512, 2) void k_fused(const unsigned short* __restrict__ q,
                                                  const unsigned short* __restrict__ kt,
                                                  const unsigned short* __restrict__ v,
                                                  const float* __restrict__ x,
                                                  const float* __restrict__ gamma,
                                                  float* __restrict__ out,
                                                  float* __restrict__ att) {
  __shared__ unsigned short smP[2][4 * 64 * 64];   // 2 x 32 KiB bf16 P tiles (4 sub-chunks)
  __shared__ float psum[8][16];

  int bid = blockIdx.x;
  int b = (bid & 7) >> 1;                       // XCD id = bid % 8
  int m0 = ((bid >> 3) * 2 + (bid & 1)) * 64;   // 64 m-tiles per batch
  int t = threadIdx.x, w = t >> 6, l = t & 63, lr = l & 15, lk = l >> 4;
  int rg = w >> 1, nh = w & 1;                  // QK^T: rows rg*16.., col-half nh
  int c0w = w * 64;                             // PV: c-rows per wave

  const unsigned short* ktb = kt + (size_t)b * NN * C8V;
  const unsigned short* vb = v + (size_t)b * CC * NN;
  float* ab = att + (size_t)b * NN * NN;

  const unsigned short* qp = q + (size_t)(b * NN + m0 + rg * 16 + lr) * C8V + lk * 8;
  bf16x8 aq0 = ldb8(qp), aq1 = ldb8(qp + 32);

  // ---- pass 1: row sums (no barriers; compiler pipelines freely) ----
  float lsum[4] = {0.f, 0.f, 0.f, 0.f};
  for (int jt = 0; jt < 64; jt++) {
    f32x4 acc2[2] = {};
#pragma unroll
    for (int cg = 0; cg < 2; cg++) {
      const unsigned short* kp = ktb + (size_t)(jt * 64 + nh * 32 + cg * 16 + lr) * C8V + lk * 8;
      acc2[cg] = MFMA16(aq0, ldb8(kp), acc2[cg]);
      acc2[cg] = MFMA16(aq1, ldb8(kp + 32), acc2[cg]);
    }
#pragma unroll
    for (int i = 0; i < 4; i++)
      lsum[i] += EXP2(acc2[0][i]) + EXP2(acc2[1][i]);
  }
#pragma unroll
  for (int i = 0; i < 4; i++) {
#pragma unroll
    for (int mm = 1; mm < 16; mm <<= 1) lsum[i] += __shfl_xor(lsum[i], mm);
  }
  if (lr == 0) {
#pragma unroll
    for (int i = 0; i < 4; i++) psum[w][lk * 4 + i] = lsum[i];
  }
  __syncthreads();
  float inv[4];
#pragma unroll
  for (int i = 0; i < 4; i++)
    inv[i] = 1.0f / (psum[rg * 2][lk * 4 + i] + psum[rg * 2 + 1][lk * 4 + i]);

  // ---- pass 2: 4-chunk batched {QKT+store} / barrier / {PV} ----
#define QKSM(BUF, U, JT)                                                       \
  {                                                                            \
    bf16x8 k0[2], k1[2];                                                       \
    _Pragma("unroll")                                                          \
    for (int cg = 0; cg < 2; cg++) {                                           \
      const unsigned short* kp =                                               \
          ktb + (size_t)((JT) * 64 + nh * 32 + cg * 16 + lr) * C8V + lk * 8;   \
      k0[cg] = ldb8(kp);                                                       \
      k1[cg] = ldb8(kp + 32);                                                  \
    }                                                                          \
    char* pbuf = reinterpret_cast<char*>(&smP[BUF][0]) + (U) * 8192;           \
    _Pragma("unroll")                                                          \
    for (int cg = 0; cg < 2; cg++) {                                           \
      f32x4 z = {};                                                            \
      z = MFMA16(aq0, k0[cg], z);                                              \
      z = MFMA16(aq1, k1[cg], z);                                              \
      int nl = nh * 32 + cg * 16 + lr;                                         \
      _Pragma("unroll")                                                        \
      for (int i = 0; i < 4; i++) {                                            \
        int ml = rg * 16 + lk * 4 + i;                                         \
        float p = EXP2(z[i]) * inv[i];                                         \
        __builtin_nontemporal_store(p, &ab[(size_t)(m0 + ml) * NN + (JT) * 64 + nl]); \
        *reinterpret_cast<unsigned short*>(                                    \
            pbuf + ml * 128 + ((nl * 2) ^ ((ml & 7) << 4))) = f2b(p);          \
      }                                                                        \
    }                                                                          \
  }

#define PVU(BUF, U, JT)                                                        \
  {                                                                            \
    const char* pr = reinterpret_cast<const char*>(&smP[BUF][0]) + (U) * 8192; \
    _Pragma("unroll")                                                          \
    for (int ks = 0; ks < 2; ks++) {                                           \
      bf16x8 bfr[4], a[4];                                                     \
      _Pragma("unroll")                                                        \
      for (int cg = 0; cg < 4; cg++) {                                         \
        int mr = cg * 16 + lr;                                                 \
        bfr[cg] = *reinterpret_cast<const bf16x8*>(                            \
            pr + mr * 128 + ((ks * 64 + lk * 16) ^ ((mr & 7) << 4)));          \
      }                                                                        \
      _Pragma("unroll")                                                        \
      for (int rg2 = 0; rg2 < 4; rg2++)                                        \
        a[rg2] = ldb8(vb + (size_t)(c0w + rg2 * 16 + lr) * NN + (JT) * 64 +    \
                      ks * 32 + lk * 8);                                       \
      _Pragma("unroll")                                                        \
      for (int rg2 = 0; rg2 < 4; rg2++)                                        \
        _Pragma("unroll")                                                      \
        for (int cg = 0; cg < 4; cg++)                                         \
          acc[rg2][cg] = MFMA16(a[rg2], bfr[cg], acc[rg2][cg]);                \
    }                                                                          \
  }

#define SYNC_NODRAIN()                                   \
  asm volatile("s_waitcnt lgkmcnt(0)" ::: "memory");     \
  __builtin_amdgcn_s_barrier();                          \
  __builtin_amdgcn_sched_barrier(0);

  f32x4 acc[4][4] = {};

  // prologue: group 0 -> buf 0
#pragma unroll
  for (int u = 0; u < 4; u++) QKSM(0, u, u);
  SYNC_NODRAIN();

  for (int g = 0; g < 16; g++) {
    int cur = g & 1;
    if (g < 15) {
#pragma unroll
      for (int u = 0; u < 4; u++) QKSM(cur ^ 1, u, (g + 1) * 4 + u);
    }
#pragma unroll
    for (int u = 0; u < 4; u++) PVU(cur, u, g * 4 + u);
    SYNC_NODRAIN();
  }
#undef QKSM
#undef PVU
#undef SYNC_NODRAIN

  // ---- epilogue: out = gamma*acc + x ----
  float gm = gamma[0];
  const float* xb = x + (size_t)b * CC * NN;
  float* ob = out + (size_t)b * CC * NN;
#pragma unroll
  for (int rg2 = 0; rg2 < 4; rg2++)
#pragma unroll
    for (int i = 0; i < 4; i++) {
      int row = c0w + rg2 * 16 + lk * 4 + i;
#pragma unroll
      for (int cg = 0; cg < 4; cg++) {
        int col = m0 + cg * 16 + lr;
        size_t off = (size_t)row * NN + col;
        float xv = __builtin_nontemporal_load(&xb[off]);
        __builtin_nontemporal_store(gm * acc[rg2][cg][i] + xv, &ob[off]);
      }
    }
}

extern "C" void kernel_launch(void* const* d_in, const int* in_sizes, int n_in,
                              void* d_out, int out_size, void* d_ws, size_t ws_size,
                              hipStream_t stream) {
  const float* x  = (const float*)d_in[0];
  const float* y  = (const float*)d_in[1];
  const float* wq = (const float*)d_in[2];
  const float* bq = (const float*)d_in[3];
  const float* wk = (const float*)d_in[4];
  const float* bk = (const float*)d_in[5];
  const float* wv = (const float*)d_in[6];
  const float* bv = (const float*)d_in[7];
  const float* gamma = (const float*)d_in[8];

  float* out = (float*)d_out;
  float* att = out + (size_t)BB * CC * NN;   // attention region of d_out

  // workspace layout (bytes)
  char* ws = (char*)d_ws;
  unsigned short* yT  = (unsigned short*)(ws);                 // 16 MiB  [B][N][C] bf16
  unsigned short* xT  = (unsigned short*)(ws + 16777216);      // 16 MiB
  unsigned short* q   = (unsigned short*)(ws + 33554432);      // 2 MiB   [B*N][64]
  unsigned short* kt  = (unsigned short*)(ws + 35651584);      // 2 MiB   [B*N][64]
  unsigned short* v   = (unsigned short*)(ws + 37748736);      // 16 MiB  [B][C][N]
  unsigned short* wqb = (unsigned short*)(ws + 54525952);      // 64 KiB
  unsigned short* wkb = (unsigned short*)(ws + 54591488);      // 64 KiB
  unsigned short* wvb = (unsigned short*)(ws + 54657024);      // 512 KiB
  if (ws_size < 55181312u) return;  // insufficient scratch -> fail loudly

  k_cvt_w<<<1280, 256, 0, stream>>>(wq, wk, wv, wqb, wkb, wvb);
  k_transpose<<<dim3(64, 8, 4), 256, 0, stream>>>(y, yT);
  k_transpose<<<dim3(64, 8, 4), 256, 0, stream>>>(x, xT);
  k_proj64<<<256, 256, 0, stream>>>(yT, wqb, bq, q, 1.44269504088896f);  // q pre-scaled by log2(e)
  k_proj64<<<256, 256, 0, stream>>>(yT, wkb, bk, kt, 1.0f);
  k_projv<<<dim3(16, 8, 4), 256, 0, stream>>>(wvb, xT, bv, v);
  k_fused<<<256, 512, 0, stream>>>(q, kt, v, x, gamma, out, att);
}